// Round 10
// baseline (222.698 us; speedup 1.0000x reference)
//
#include <hip/hip_runtime.h>

#define BB 8
#define CC 256
#define DD 128
#define NN 4096

#define LOG2E 1.44269504f
#define MSHIFT 32.0f  // fixed softmax shift (base-2 domain); |S*log2e| << 32 always

typedef __attribute__((ext_vector_type(8))) short short8;
typedef __attribute__((ext_vector_type(4))) short short4v;
typedef __attribute__((ext_vector_type(4))) float f32x4;
typedef __attribute__((ext_vector_type(16))) float f32x16;
typedef __attribute__((ext_vector_type(4))) unsigned int u32x4;

static __device__ __forceinline__ unsigned short f2bf(float f) {
    unsigned u = __builtin_bit_cast(unsigned, f);
    u += 0x7FFFu + ((u >> 16) & 1u);
    return (unsigned short)(u >> 16);
}
static __device__ __forceinline__ float bf2f(unsigned short h) {
    unsigned u = ((unsigned)h) << 16;
    return __builtin_bit_cast(float, u);
}
static __device__ __forceinline__ short8 pack8(float4 a, float4 b) {
    short8 r;
    r[0] = (short)f2bf(a.x); r[1] = (short)f2bf(a.y);
    r[2] = (short)f2bf(a.z); r[3] = (short)f2bf(a.w);
    r[4] = (short)f2bf(b.x); r[5] = (short)f2bf(b.y);
    r[6] = (short)f2bf(b.z); r[7] = (short)f2bf(b.w);
    return r;
}
// packed f32x2 -> bf16x2 (RNE); element 0 in low 16 bits
static __device__ __forceinline__ unsigned cvtpk_bf16(float lo, float hi) {
    unsigned r;
    asm("v_cvt_pk_bf16_f32 %0, %1, %2" : "=v"(r) : "v"(lo), "v"(hi));
    return r;
}
// swap upper 32 lanes of a with lower 32 lanes of b (T12 primitive)
static __device__ __forceinline__ void pl32swap(unsigned &a, unsigned &b) {
#if __has_builtin(__builtin_amdgcn_permlane32_swap)
    auto r = __builtin_amdgcn_permlane32_swap((int)a, (int)b, false, false);
    a = (unsigned)r[0]; b = (unsigned)r[1];
#else
    asm("v_permlane32_swap_b32 %0, %1" : "+v"(a), "+v"(b));
#endif
}
// async global->LDS DMA, 16 B/lane: LDS dest = wave-uniform base + lane*16 (m97/m104)
static __device__ __forceinline__ void gll16(const void* g, void* l) {
    __builtin_amdgcn_global_load_lds(
        (const __attribute__((address_space(1))) unsigned int*)g,
        (__attribute__((address_space(3))) unsigned int*)l, 16, 0, 0);
}
// counted VMEM wait (T4): literal-immediate variants; memory clobber pins mem ops
#define VMWAIT(N) asm volatile("s_waitcnt vmcnt(" #N ")" ::: "memory")

// ---------------- kernel 2: FUSED projections (x read ONCE; 3 MFMAs per B-frag) -------
// grid (NN/128, BB) = 256 blocks, block 512 = 8 waves; wave owns d-range (wave&3)*32,
// n-range (wave>>2)*64. Per kc chunk: stage x^T [128n][64c] bf16 into LDS (lane-contiguous
// fp32 reads, col swizzle (c + 8*(n>>4)) & 63), then accumulate theta/phi/g together.
// Outputs: Q=theta*log2e [n][d], K=phi [n][d], Vt=g [d][n]. Replaces 3 passes over x.
__global__ __launch_bounds__(512, 2) void k_proj(
        const float* __restrict__ x,
        const float* __restrict__ w_phi, const float* __restrict__ b_phi,
        const float* __restrict__ w_theta, const float* __restrict__ b_theta,
        const float* __restrict__ w_g, const float* __restrict__ b_g,
        unsigned short* __restrict__ qws, unsigned short* __restrict__ kws,
        unsigned short* __restrict__ vtws) {
    __shared__ __align__(16) unsigned short xs[128][72];     // staged x^T chunk (18432 B)
    __shared__ __align__(16) unsigned short rp[128][136];    // repack buffer (34816 B)
    int nb = blockIdx.x * 128, b = blockIdx.y;
    int t = threadIdx.x, lane = t & 63, wave = t >> 6;
    int l16 = lane & 15, l4 = lane >> 4;
    int wd = wave & 3, wn = wave >> 2;  // d-range wd*32, n-range wn*64

    f32x4 a_th[2][4], a_ph[2][4], a_g[2][4];
#pragma unroll
    for (int mf = 0; mf < 2; mf++)
#pragma unroll
        for (int nf = 0; nf < 4; nf++)
#pragma unroll
            for (int e = 0; e < 4; e++) { a_th[mf][nf][e] = 0.f; a_ph[mf][nf][e] = 0.f; a_g[mf][nf][e] = 0.f; }

    const float* xpb = x + (size_t)b * CC * NN;  // [c][n]

    for (int kc = 0; kc < 4; kc++) {
        int c0k = kc * 64;
        __syncthreads();
        {   // stage 64c x 128n: 2048 float4, lane-contiguous (1 KB/wave-instr)
            float4 xv[4];
#pragma unroll
            for (int j = 0; j < 4; j++) {
                int idx = t + 512 * j;
                int cr = idx >> 5, pos = idx & 31;
                xv[j] = *(const float4*)(xpb + (size_t)(c0k + cr) * NN + nb + pos * 4);
            }
#pragma unroll
            for (int j = 0; j < 4; j++) {
                int idx = t + 512 * j;
                int cr = idx >> 5, pos = idx & 31;
                int col = (cr + 8 * (pos >> 2)) & 63;
                xs[pos * 4 + 0][col] = f2bf(xv[j].x);
                xs[pos * 4 + 1][col] = f2bf(xv[j].y);
                xs[pos * 4 + 2][col] = f2bf(xv[j].z);
                xs[pos * 4 + 3][col] = f2bf(xv[j].w);
            }
        }
        __syncthreads();
        // weight A-frags for this c-chunk (L2-resident after first block)
        short8 af_t[2][2], af_p[2][2], af_g[2][2];  // [mf][ic]
#pragma unroll
        for (int mf = 0; mf < 2; mf++)
#pragma unroll
            for (int ic = 0; ic < 2; ic++) {
                int d = wd * 32 + mf * 16 + l16;
                int co = c0k + ic * 32 + l4 * 8;
                const float* wpt = w_theta + d * CC + co;
                const float* wpp = w_phi   + d * CC + co;
                const float* wpg = w_g     + d * CC + co;
                af_t[mf][ic] = pack8(*(const float4*)wpt, *(const float4*)(wpt + 4));
                af_p[mf][ic] = pack8(*(const float4*)wpp, *(const float4*)(wpp + 4));
                af_g[mf][ic] = pack8(*(const float4*)wpg, *(const float4*)(wpg + 4));
            }
#pragma unroll
        for (int nf = 0; nf < 4; nf++)
#pragma unroll
            for (int ic = 0; ic < 2; ic++) {
                int ncol = (ic * 32 + l4 * 8 + 8 * (wn * 4 + nf)) & 63;
                short8 bfr = *(const short8*)&xs[wn * 64 + nf * 16 + l16][ncol];
                a_th[0][nf] = __builtin_amdgcn_mfma_f32_16x16x32_bf16(af_t[0][ic], bfr, a_th[0][nf], 0, 0, 0);
                a_th[1][nf] = __builtin_amdgcn_mfma_f32_16x16x32_bf16(af_t[1][ic], bfr, a_th[1][nf], 0, 0, 0);
                a_ph[0][nf] = __builtin_amdgcn_mfma_f32_16x16x32_bf16(af_p[0][ic], bfr, a_ph[0][nf], 0, 0, 0);
                a_ph[1][nf] = __builtin_amdgcn_mfma_f32_16x16x32_bf16(af_p[1][ic], bfr, a_ph[1][nf], 0, 0, 0);
                a_g[0][nf]  = __builtin_amdgcn_mfma_f32_16x16x32_bf16(af_g[0][ic], bfr, a_g[0][nf], 0, 0, 0);
                a_g[1][nf]  = __builtin_amdgcn_mfma_f32_16x16x32_bf16(af_g[1][ic], bfr, a_g[1][nf], 0, 0, 0);
            }
    }
    // acc C-layout: col(l16) = n-within-frag, row(l4*4+r) = d-within-frag
    __syncthreads();  // xs reads done (rp disjoint, but keep phases clean)

    // ---- Q = theta * log2e, [n][d] ----
#pragma unroll
    for (int mf = 0; mf < 2; mf++) {
        int d0 = wd * 32 + mf * 16 + l4 * 4;
        float bb[4];
#pragma unroll
        for (int r = 0; r < 4; r++) bb[r] = b_theta[d0 + r];
#pragma unroll
        for (int nf = 0; nf < 4; nf++) {
            short4v pk;
#pragma unroll
            for (int r = 0; r < 4; r++) pk[r] = (short)f2bf((a_th[mf][nf][r] + bb[r]) * LOG2E);
            *(short4v*)&rp[wn * 64 + nf * 16 + l16][d0] = pk;
        }
    }
    __syncthreads();
    {
        unsigned short* outp = qws + (size_t)b * NN * DD;
#pragma unroll
        for (int i = 0; i < 4; i++) {
            int idx = t + 512 * i;
            int n = idx >> 4, dd = (idx & 15) * 8;
            *(short8*)(outp + (size_t)(nb + n) * DD + dd) = *(const short8*)&rp[n][dd];
        }
    }
    __syncthreads();

    // ---- K = phi, [n][d] ----
#pragma unroll
    for (int mf = 0; mf < 2; mf++) {
        int d0 = wd * 32 + mf * 16 + l4 * 4;
        float bb[4];
#pragma unroll
        for (int r = 0; r < 4; r++) bb[r] = b_phi[d0 + r];
#pragma unroll
        for (int nf = 0; nf < 4; nf++) {
            short4v pk;
#pragma unroll
            for (int r = 0; r < 4; r++) pk[r] = (short)f2bf(a_ph[mf][nf][r] + bb[r]);
            *(short4v*)&rp[wn * 64 + nf * 16 + l16][d0] = pk;
        }
    }
    __syncthreads();
    {
        unsigned short* outp = kws + (size_t)b * NN * DD;
#pragma unroll
        for (int i = 0; i < 4; i++) {
            int idx = t + 512 * i;
            int n = idx >> 4, dd = (idx & 15) * 8;
            *(short8*)(outp + (size_t)(nb + n) * DD + dd) = *(const short8*)&rp[n][dd];
        }
    }
    __syncthreads();

    // ---- Vt = g, [d][n] ----
#pragma unroll
    for (int mf = 0; mf < 2; mf++) {
        int drow = wd * 32 + mf * 16 + l4 * 4;
        float bb[4];
#pragma unroll
        for (int r = 0; r < 4; r++) bb[r] = b_g[drow + r];
#pragma unroll
        for (int nf = 0; nf < 4; nf++)
#pragma unroll
            for (int r = 0; r < 4; r++)
                rp[drow + r][wn * 64 + nf * 16 + l16] = f2bf(a_g[mf][nf][r] + bb[r]);
    }
    __syncthreads();
    {
        unsigned short* outp = vtws + (size_t)b * DD * NN;
#pragma unroll
        for (int i = 0; i < 4; i++) {
            int idx = t + 512 * i;
            int d = idx >> 4, n0s = (idx & 15) * 8;
            *(short8*)(outp + (size_t)d * NN + nb + n0s) = *(const short8*)&rp[d][n0s];
        }
    }
}

// ---------------- kernel 3: flash attention — ring-4 + T15 pipeline (QK(t+1) ∥ SM/PV(t)) --
// r8-verified ring-4/counted-vmcnt skeleton. T15: iteration t interleaves softmax(t)+PV(t)
// (VALU + 8 MFMA) with QK^T(t+1) (8 MFMA, independent) — exp2/cvt ops sit between the
// dependent QK MFMAs so the chain latency is hidden (r9 lesson: bare dist-1 chain stalls).
// vmcnt(4) before the barrier drains tile t+1 (FIFO: outstanding t+1(4)+t+2(4)=8 -> 4);
// wait-BEFORE-barrier publishes all waves' segments. Ring-4 slot distances: write t+2,
// read K t+1, read V t, laggard reads t-1 -> pairwise distinct mod 4. All pipeline state
// in statically-named registers (macro, no lambda - r3 lesson). Final iter's QK reads a
// stale slot into a dead register (branch-free). grid 512 = 2 blocks/CU, 8 waves/CU.
#define QKSTEP(SN, KBN, KC) \
    SN = __builtin_amdgcn_mfma_f32_32x32x16_bf16( \
        *(const short8*)((KBN) + kvo[KC]), qreg[KC], SN, 0, 0, 0);

#define PABUILD(PA, Pa, Pb, Pc, Pd, Pe, Pf_, Pg, Ph) {                                \
    unsigned x0 = cvtpk_bf16(Pa, Pb);                                                 \
    unsigned x1 = cvtpk_bf16(Pc, Pd);                                                 \
    unsigned y0 = cvtpk_bf16(Pe, Pf_);                                                \
    unsigned y1 = cvtpk_bf16(Pg, Ph);                                                 \
    pl32swap(x0, y0); pl32swap(x1, y1);                                               \
    PA[0] = x0; PA[1] = x1; PA[2] = y0; PA[3] = y1; }

#define FBODY(IT, SC, SN) {                                                           \
    if ((IT) + 2 < NIT) {                                                             \
        int mb2 = kbase + ((IT) + 2) * 32;                                            \
        char* W = (char*)smem + (((IT) + 2) & 3) * 16384;                             \
        gll16(kp + (size_t)mb2 * DD + koff[0], W + (wave * 2 + 0) * 1024);            \
        gll16(kp + (size_t)mb2 * DD + koff[1], W + (wave * 2 + 1) * 1024);            \
        gll16(vp + mb2 + voff[0], W + 8192 + (wave * 2 + 0) * 1024);                  \
        gll16(vp + mb2 + voff[1], W + 8192 + (wave * 2 + 1) * 1024);                  \
        VMWAIT(4);                                                                    \
    } else {                                                                          \
        VMWAIT(0);                                                                    \
    }                                                                                 \
    __builtin_amdgcn_s_barrier();                                                     \
    asm volatile("" ::: "memory");                                                    \
    char* KbN = (char*)smem + (((IT) + 1) & 3) * 16384;                               \
    char* Vb  = (char*)smem + ((IT) & 3) * 16384 + 8192;                              \
    _Pragma("unroll") for (int e = 0; e < 16; e++) SN[e] = -MSHIFT;                   \
    float p0, p1, p2, p3, p4, p5, p6, p7, p8, p9, p10, p11, p12, p13, p14, p15;       \
    __builtin_amdgcn_s_setprio(1);                                                    \
    p0 = __builtin_exp2f(SC[0]);  lsum0 += p0;                                        \
    p1 = __builtin_exp2f(SC[1]);  lsum1 += p1;                                        \
    p2 = __builtin_exp2f(SC[2]);  lsum0 += p2;                                        \
    p3 = __builtin_exp2f(SC[3]);  lsum1 += p3;                                        \
    QKSTEP(SN, KbN, 0) QKSTEP(SN, KbN, 1)                                             \
    p4 = __builtin_exp2f(SC[4]);  lsum0 += p4;                                        \
    p5 = __builtin_exp2f(SC[5]);  lsum1 += p5;                                        \
    p6 = __builtin_exp2f(SC[6]);  lsum0 += p6;                                        \
    p7 = __builtin_exp2f(SC[7]);  lsum1 += p7;                                        \
    QKSTEP(SN, KbN, 2) QKSTEP(SN, KbN, 3)                                             \
    u32x4 paA; PABUILD(paA, p0, p1, p2, p3, p4, p5, p6, p7)                           \
    p8  = __builtin_exp2f(SC[8]);  lsum0 += p8;                                       \
    p9  = __builtin_exp2f(SC[9]);  lsum1 += p9;                                       \
    p10 = __builtin_exp2f(SC[10]); lsum0 += p10;                                      \
    p11 = __builtin_exp2f(SC[11]); lsum1 += p11;                                      \
    QKSTEP(SN, KbN, 4) QKSTEP(SN, KbN, 5)                                             \
    p12 = __builtin_exp2f(SC[12]); lsum0 += p12;                                      \
    p13 = __builtin_exp2f(SC[13]); lsum1 += p13;                                      \
    p14 = __builtin_exp2f(SC[14]); lsum0 += p14;                                      \
    p15 = __builtin_exp2f(SC[15]); lsum1 += p15;                                      \
    QKSTEP(SN, KbN, 6) QKSTEP(SN, KbN, 7)                                             \
    u32x4 paB; PABUILD(paB, p8, p9, p10, p11, p12, p13, p14, p15)                     \
    o[0] = __builtin_amdgcn_mfma_f32_32x32x16_bf16(                                   \
        __builtin_bit_cast(short8, paA), *(const short8*)(Vb + 0 * 2048 + vvo[0]), o[0], 0, 0, 0); \
    o[1] = __builtin_amdgcn_mfma_f32_32x32x16_bf16(                                   \
        __builtin_bit_cast(short8, paA), *(const short8*)(Vb + 1 * 2048 + vvo[0]), o[1], 0, 0, 0); \
    o[2] = __builtin_amdgcn_mfma_f32_32x32x16_bf16(                                   \
        __builtin_bit_cast(short8, paA), *(const short8*)(Vb + 2 * 2048 + vvo[0]), o[2], 0, 0, 0); \
    o[3] = __builtin_amdgcn_mfma_f32_32x32x16_bf16(                                   \
        __builtin_bit_cast(short8, paA), *(const short8*)(Vb + 3 * 2048 + vvo[0]), o[3], 0, 0, 0); \
    o[0] = __builtin_amdgcn_mfma_f32_32x32x16_bf16(                                   \
        __builtin_bit_cast(short8, paB), *(const short8*)(Vb + 0 * 2048 + vvo[1]), o[0], 0, 0, 0); \
    o[1] = __builtin_amdgcn_mfma_f32_32x32x16_bf16(                                   \
        __builtin_bit_cast(short8, paB), *(const short8*)(Vb + 1 * 2048 + vvo[1]), o[1], 0, 0, 0); \
    o[2] = __builtin_amdgcn_mfma_f32_32x32x16_bf16(                                   \
        __builtin_bit_cast(short8, paB), *(const short8*)(Vb + 2 * 2048 + vvo[1]), o[2], 0, 0, 0); \
    o[3] = __builtin_amdgcn_mfma_f32_32x32x16_bf16(                                   \
        __builtin_bit_cast(short8, paB), *(const short8*)(Vb + 3 * 2048 + vvo[1]), o[3], 0, 0, 0); \
    __builtin_amdgcn_s_setprio(0);                                                    \
}

__global__ __launch_bounds__(256, 2) void k_flash(
        const unsigned short* __restrict__ q, const unsigned short* __restrict__ kk,
        const unsigned short* __restrict__ vt, unsigned short* __restrict__ opart,
        float* __restrict__ lsums) {
    __shared__ __align__(16) unsigned char smem[65536];
    // buf i at smem + i*16384: K (32 rows x 256 B) at +0, V (128 rows x 64 B) at +8192

    int bid = blockIdx.x;
    int b   = bid & 7;           // batch -> XCD (round-robin dispatch): K/V L2-resident
    int rem = bid >> 3;          // 0..63
    int ks  = rem >> 5;          // 0..1
    int qt  = rem & 31;          // 0..31
    int qb  = qt * 128;

    int t = threadIdx.x, lane = t & 63, wave = t >> 6;  // wave 0..3
    int l31 = lane & 31, hi = lane >> 5;

    const unsigned short* qp = q  + (size_t)b * NN * DD;
    const unsigned short* kp = kk + (size_t)b * NN * DD;
    const unsigned short* vp = vt + (size_t)b * DD * NN;

    // Q fragments (B-operand of swapped QK^T): lane holds Q[qb+w*32+l31][kc*16+hi*8+e]
    short8 qreg[8];
    {
        int qrow = qb + wave * 32 + l31;
#pragma unroll
        for (int kc = 0; kc < 8; kc++)
            qreg[kc] = *(const short8*)(qp + (size_t)qrow * DD + kc * 16 + hi * 8);
    }

    // per-lane DMA source offsets (elements): wave stages 2 K-segs + 2 V-segs (1024 B each).
    // K seg s covers rows 4s..4s+3; src chunk = c' ^ (row&7) -> LDS[row][c'] = swizzled.
    // V seg s covers d-rows 16s..16s+15; src chunk = c' ^ ((row^(row>>2))&3).
    int koff[2], voff[2];
#pragma unroll
    for (int j = 0; j < 2; j++) {
        int seg = wave * 2 + j;
        int krow = seg * 4 + (lane >> 4);
        koff[j] = krow * DD + (((lane & 15) ^ (krow & 7)) << 3);
        int vrow = seg * 16 + (lane >> 2);
        voff[j] = vrow * NN + (((lane & 3) ^ ((vrow ^ (vrow >> 2)) & 3)) << 3);
    }

    // loop-invariant LDS READ byte-offsets (within a ring slot):
    // K: kvo[kc] = l31*256 + (((kc<<1|hi) ^ (l31&7)) << 4)
    // V: vvo[c]  = l31*64  + (((c<<1|hi) ^ ((l31^(l31>>2))&3)) << 4); read at +df*2048
    int kvo[8], vvo[2];
    {
        int e = l31 & 7;
#pragma unroll
        for (int kc = 0; kc < 8; kc++)
            kvo[kc] = l31 * 256 + ((((kc << 1) | hi) ^ e) << 4);
        int sw = (l31 ^ (l31 >> 2)) & 3;
#pragma unroll
        for (int c = 0; c < 2; c++)
            vvo[c] = l31 * 64 + ((((c << 1) | hi) ^ sw) << 4);
    }

    f32x16 o[4];
#pragma unroll
    for (int df = 0; df < 4; df++)
#pragma unroll
        for (int e = 0; e < 16; e++) o[df][e] = 0.f;
    float lsum0 = 0.f, lsum1 = 0.f;

    int kbase = ks * (NN / 2);
    const int NIT = (NN / 2) / 32;  // 64

    // prologue: issue DMA for tiles 0 and 1; drain tile 0; QK(0) -> s0
#pragma unroll
    for (int pt = 0; pt < 2; pt++) {
        int mb = kbase + pt * 32;
        char* Kb = (char*)smem + pt * 16384;
#pragma unroll
        for (int j = 0; j < 2; j++) {
            int seg = wave * 2 + j;
            gll16(kp + (size_t)mb * DD + koff[j], Kb + seg * 1024);
            gll16(vp + mb + voff[j], Kb + 8192 + seg * 1024);
        }
    }
    VMWAIT(4);
    __builtin_amdgcn_s_barrier();
    asm volatile("" ::: "memory");

    f32x16 s0, s1;
#pragma unroll
    for (int e = 0; e < 16; e++) s0[e] = -MSHIFT;
    {
        char* Kb0 = (char*)smem;
        __builtin_amdgcn_s_setprio(1);
        QKSTEP(s0, Kb0, 0) QKSTEP(s0, Kb0, 1) QKSTEP(s0, Kb0, 2) QKSTEP(s0, Kb0, 3)
        QKSTEP(s0, Kb0, 4) QKSTEP(s0, Kb0, 5) QKSTEP(s0, Kb0, 6) QKSTEP(s0, Kb0, 7)
        __builtin_amdgcn_s_setprio(0);
    }

    for (int it = 0; it < NIT; it += 2) {
        FBODY(it, s0, s1)
        FBODY(it + 1, s1, s0)
    }

    // ---- epilogue: row-sums + staged coalesced O-partial store ----
    {
        float lsum = lsum0 + lsum1;
        float tot = lsum + __shfl_xor(lsum, 32);
        if (lane < 32)
            lsums[((size_t)ks * BB + b) * NN + qb + wave * 32 + l31] = tot;
    }
    __syncthreads();  // full drain once: all waves done with ring bufs before Ox overlay
    unsigned short (*Ox)[136] = (unsigned short (*)[136])smem;  // 128 x 136 (34816 B)
#pragma unroll
    for (int df = 0; df < 4; df++)
#pragma unroll
        for (int r = 0; r < 16; r++) {
            int qr = (r & 3) + 8 * (r >> 2) + 4 * hi;
            Ox[wave * 32 + qr][df * 32 + l31] = f2bf(o[df][r]);
        }
    __syncthreads();
    unsigned short* op = opart + (((size_t)ks * BB + b) * NN + qb) * DD;
#pragma unroll
    for (int i = 0; i < 8; i++) {
        int idx = t + 256 * i;  // 0..2047
        int nr = idx >> 4, c0 = (idx & 15) * 8;
        *(short8*)(op + (size_t)nr * DD + c0) = *(const short8*)&Ox[nr][c0];
    }
}

// ---------------- kernel 4: combine partials + out = w_mask . y^T + b_mask + x ----------------
// grid (NN/64, BB), block 256; BOTH c-halves per block (opart/Ys staged once, cs loop).
// Ys and Os are disjoint LDS regions (52.5 KB total) -> 2 blocks/CU.
__global__ __launch_bounds__(256) void k_maskout(
        const unsigned short* __restrict__ opart, const float* __restrict__ lsums,
        const float* __restrict__ w_mask, const float* __restrict__ b_mask,
        const float* __restrict__ x, float* __restrict__ out) {
    __shared__ __align__(16) unsigned char pool[52480];
    unsigned short (*Ys)[136] = (unsigned short (*)[136])pool;   // 64x136x2B = 17408
    float (*Os)[68] = (float (*)[68])(pool + 17408);             // 128x68x4B = 34816
    float* invl = (float*)(pool + 52224);                        // 256 B
    int nb = blockIdx.x * 64, b = blockIdx.y;
    int t = threadIdx.x, lane = t & 63, wave = t >> 6;
    int l16 = lane & 15, l4 = lane >> 4;

    const unsigned short* o0 = opart + ((size_t)b * NN + nb) * DD;
    const unsigned short* o1 = opart + (((size_t)BB + b) * NN + nb) * DD;
    if (t < 64) {
        float ls0 = lsums[(size_t)b * NN + nb + t];
        float ls1 = lsums[((size_t)BB + b) * NN + nb + t];
        invl[t] = 1.0f / (ls0 + ls1);
    }
    __syncthreads();
#pragma unroll
    for (int i = 0; i < 4; i++) {  // combine the 2 key-split partials while staging y
        int idx = t + 256 * i;
        int nr = idx >> 4, d0 = (idx & 15) * 8;
        short8 a = *(const short8*)(o0 + (size_t)nr * DD + d0);
        short8 c = *(const short8*)(o1 + (size_t)nr * DD + d0);
        float inv = invl[nr];
        short8 yv;
#pragma unroll
        for (int j = 0; j < 8; j++)
            yv[j] = (short)f2bf((bf2f((unsigned short)a[j]) + bf2f((unsigned short)c[j])) * inv);
        *(short8*)&Ys[nr][d0] = yv;
    }
    __syncthreads();

    for (int cs = 0; cs < 2; cs++) {
        f32x4 acc[2][4];
#pragma unroll
        for (int mf = 0; mf < 2; mf++)
#pragma unroll
            for (int nf = 0; nf < 4; nf++)
#pragma unroll
                for (int e = 0; e < 4; e++) acc[mf][nf][e] = 0.f;

#pragma unroll
        for (int kc = 0; kc < 4; kc++) {
            int d0 = kc * 32 + l4 * 8;
            short8 af[2];
#pragma unroll
            for (int mf = 0; mf < 2; mf++) {
                int c = cs * 128 + wave * 32 + mf * 16 + l16;
                const float* wp = w_mask + c * DD + d0;
                af[mf] = pack8(*(const float4*)wp, *(const float4*)(wp + 4));
            }
#pragma unroll
            for (int nf = 0; nf < 4; nf++) {
                short8 bfr = *(const short8*)&Ys[nf * 16 + l16][d0];
#pragma unroll
                for (int mf = 0; mf < 2; mf++)
                    acc[mf][nf] = __builtin_amdgcn_mfma_f32_16x16x32_bf16(af[mf], bfr, acc[mf][nf], 0, 0, 0);
            }
        }
        __syncthreads();  // cs=1: previous epilogue's Os reads done (no-op cost at cs=0)

        // stage acc + bias into Os[128][68] fp32
#pragma unroll
        for (int mf = 0; mf < 2; mf++) {
            int c0 = wave * 32 + mf * 16 + l4 * 4;  // local c 0..127
            float bb[4];
#pragma unroll
            for (int r = 0; r < 4; r++) bb[r] = b_mask[cs * 128 + c0 + r];
#pragma unroll
            for (int r = 0; r < 4; r++)
#pragma unroll
                for (int nf = 0; nf < 4; nf++)
                    Os[c0 + r][nf * 16 + l16] = acc[mf][nf][r] + bb[r];
        }
        __syncthreads();

        // vectorized epilogue: out = Os + x (float4; 256B contiguous per c-row)
        const float* xp = x + (size_t)b * CC * NN + (size_t)cs * 128 * NN + nb;
        float* op = out + (size_t)b * CC * NN + (size_t)cs * 128 * NN + nb;
#pragma unroll
        for (int i = 0; i < 8; i++) {
            int idx = t + 256 * i;        // 0..2047
            int c = idx >> 4, nq = (idx & 15) * 4;
            float4 osv = *(const float4*)&Os[c][nq];
            float4 xv = *(const float4*)(xp + (size_t)c * NN + nq);
            float4 ov;
            ov.x = osv.x + xv.x; ov.y = osv.y + xv.y;
            ov.z = osv.z + xv.z; ov.w = osv.w + xv.w;
            *(float4*)(op + (size_t)c * NN + nq) = ov;
        }
    }
}

extern "C" void kernel_launch(void* const* d_in, const int* in_sizes, int n_in,
                              void* d_out, int out_size, void* d_ws, size_t ws_size,
                              hipStream_t stream) {
    const float* x       = (const float*)d_in[0];
    const float* w_phi   = (const float*)d_in[1];
    const float* b_phi   = (const float*)d_in[2];
    const float* w_theta = (const float*)d_in[3];
    const float* b_theta = (const float*)d_in[4];
    const float* w_g     = (const float*)d_in[5];
    const float* b_g     = (const float*)d_in[6];
    const float* w_mask  = (const float*)d_in[7];
    const float* b_mask  = (const float*)d_in[8];
    float* out = (float*)d_out;

    // ws (48 MiB): [0,16M): Opart (2*8*4096*128 bf16 = 16 MiB)
    //              [16,24M): Q | [24,32M): K | [32,40M): Vt | [40M+): lsums (256 KiB)
    char* ws = (char*)d_ws;
    unsigned short* opart = (unsigned short*)(ws);
    unsigned short* qw    = (unsigned short*)(ws + ((size_t)16 << 20));
    unsigned short* kw    = (unsigned short*)(ws + ((size_t)24 << 20));
    unsigned short* vtw   = (unsigned short*)(ws + ((size_t)32 << 20));
    float*          lsums = (float*)(ws + ((size_t)40 << 20));

    k_proj<<<dim3(NN / 128, BB), 512, 0, stream>>>(x, w_phi, b_phi, w_theta, b_theta,
                                                   w_g, b_g, qw, kw, vtw);
    k_flash<<<dim3(512, 1, 1), 256, 0, stream>>>(qw, kw, vtw, opart, lsums);
    k_maskout<<<dim3(NN / 64, BB), 256, 0, stream>>>(opart, lsums, w_mask, b_mask, x, out);
}